// Round 1
// baseline (463.859 us; speedup 1.0000x reference)
//
#include <hip/hip_runtime.h>

#define B_ 16
#define D_ 768
#define N_ 4096
#define Q_ 128

typedef __attribute__((ext_vector_type(4))) float f32x4;
typedef __attribute__((ext_vector_type(8))) short short8;
typedef __attribute__((ext_vector_type(4))) short sv4;

__device__ __forceinline__ unsigned short f2bf(float f) {
  union { float f; unsigned u; } x; x.f = f;
  unsigned u = x.u;
  unsigned r = u + 0x7fffu + ((u >> 16) & 1u);
  return (unsigned short)(r >> 16);
}
__device__ __forceinline__ float bf2f(unsigned short h) {
  union { unsigned u; float f; } x; x.u = ((unsigned)h) << 16;
  return x.f;
}

// ---------------- elementwise cast fp32 -> bf16 (4/thread) ----------------
__global__ __launch_bounds__(256) void cast_bf16_kernel(
    const float* __restrict__ src, unsigned short* __restrict__ dst, int n4) {
  int i = blockIdx.x * 256 + threadIdx.x;
  if (i >= n4) return;
  float4 v = ((const float4*)src)[i];
  ushort4 o;
  o.x = f2bf(v.x); o.y = f2bf(v.y); o.z = f2bf(v.z); o.w = f2bf(v.w);
  ((ushort4*)dst)[i] = o;
}

// ---------------- transpose + cast (for Wq -> WqT) ----------------
__global__ __launch_bounds__(256) void transpose_cast_kernel(
    const float* __restrict__ src, unsigned short* __restrict__ dst, int rows, int cols) {
  __shared__ float tile[32][33];
  int bx = blockIdx.x * 32, by = blockIdx.y * 32;
  int tx = threadIdx.x & 31, ty = threadIdx.x >> 5;
  #pragma unroll
  for (int i = 0; i < 32; i += 8)
    tile[ty + i][tx] = src[(size_t)(by + ty + i) * cols + bx + tx];
  __syncthreads();
  #pragma unroll
  for (int i = 0; i < 32; i += 8)
    dst[(size_t)(bx + ty + i) * rows + by + tx] = f2bf(tile[tx][ty + i]);
}

// ---------------- per-row entropy of softmax (text rows), one wave/row ----------------
__global__ __launch_bounds__(256) void row_entropy_kernel(
    const float* __restrict__ X, float* __restrict__ ent, int K) {
  int row = blockIdx.x * 4 + (threadIdx.x >> 6);
  int lane = threadIdx.x & 63;
  const float* x = X + (size_t)row * K;
  float m = -__builtin_inff(), s = 0.f, t = 0.f;
  for (int k = lane; k < K; k += 64) {
    float v = x[k];
    float nm = fmaxf(m, v);
    float c = __expf(m - nm);
    float e = __expf(v - nm);
    s = s * c + e;
    t = t * c + v * e;
    m = nm;
  }
  #pragma unroll
  for (int off = 32; off > 0; off >>= 1) {
    float m2 = __shfl_xor(m, off);
    float s2 = __shfl_xor(s, off);
    float t2 = __shfl_xor(t, off);
    float nm = fmaxf(m, m2);
    float c1 = __expf(m - nm), c2 = __expf(m2 - nm);
    s = s * c1 + s2 * c2;
    t = t * c1 + t2 * c2;
    m = nm;
  }
  if (lane == 0) ent[row] = m + __logf(s) - t / s;
}

// ---------------- visual entropy: 64 tokens/block, 4 d-slices of 192 ----------------
__global__ __launch_bounds__(256) void visual_entropy_kernel(
    const float* __restrict__ vis, float* __restrict__ ent) {
  int bb = blockIdx.x >> 6;
  int n0 = (blockIdx.x & 63) * 64;
  int t = threadIdx.x;
  int tok = t & 63;
  int slice = t >> 6;
  const float* base = vis + (size_t)bb * D_ * N_ + (size_t)slice * 192 * N_ + n0 + tok;
  float m = -__builtin_inff(), s = 0.f, tt = 0.f;
  for (int d = 0; d < 192; d++) {
    float v = base[(size_t)d * N_];
    float nm = fmaxf(m, v);
    float c = __expf(m - nm);
    float e = __expf(v - nm);
    s = s * c + e; tt = tt * c + v * e; m = nm;
  }
  __shared__ float sm[256], ss[256], st[256];
  sm[t] = m; ss[t] = s; st[t] = tt;
  __syncthreads();
  if (t < 64) {
    #pragma unroll
    for (int k = 1; k < 4; k++) {
      float m2 = sm[t + 64 * k], s2 = ss[t + 64 * k], t2 = st[t + 64 * k];
      float nm = fmaxf(m, m2);
      float c1 = __expf(m - nm), c2 = __expf(m2 - nm);
      s = s * c1 + s2 * c2; tt = tt * c1 + t2 * c2; m = nm;
    }
    ent[(size_t)bb * N_ + n0 + t] = m + __logf(s) - tt / s;
  }
}

// ---------------- softmax over 128 (te), one block/batch ----------------
__global__ __launch_bounds__(128) void softmax128_kernel(
    const float* __restrict__ ent, float* __restrict__ w) {
  int b = blockIdx.x, t = threadIdx.x;
  float v = ent[b * 128 + t];
  float m = v;
  #pragma unroll
  for (int off = 32; off; off >>= 1) m = fmaxf(m, __shfl_xor(m, off));
  __shared__ float sm2[2], ssum[2];
  int wv = t >> 6;
  if ((t & 63) == 0) sm2[wv] = m;
  __syncthreads();
  m = fmaxf(sm2[0], sm2[1]);
  float e = __expf(v - m);
  float s = e;
  #pragma unroll
  for (int off = 32; off; off >>= 1) s += __shfl_xor(s, off);
  if ((t & 63) == 0) ssum[wv] = s;
  __syncthreads();
  s = ssum[0] + ssum[1];
  w[b * 128 + t] = e / s;
}

// ---------------- softmax over 4096 (ve), one block/batch, 1024 thr ----------------
__global__ __launch_bounds__(1024) void softmax4096_kernel(
    const float* __restrict__ ent, float* __restrict__ w) {
  int b = blockIdx.x, t = threadIdx.x;
  const float* e = ent + (size_t)b * N_;
  float v[4];
  float m = -__builtin_inff();
  #pragma unroll
  for (int i = 0; i < 4; i++) { v[i] = e[t + 1024 * i]; m = fmaxf(m, v[i]); }
  #pragma unroll
  for (int off = 32; off; off >>= 1) m = fmaxf(m, __shfl_xor(m, off));
  __shared__ float red[16];
  int wv = t >> 6;
  if ((t & 63) == 0) red[wv] = m;
  __syncthreads();
  if (t < 16) {
    float x = red[t];
    #pragma unroll
    for (int off = 8; off; off >>= 1) x = fmaxf(x, __shfl_xor(x, off));
    red[t] = x;
  }
  __syncthreads();
  m = red[0];
  float ev[4];
  float s = 0.f;
  #pragma unroll
  for (int i = 0; i < 4; i++) { ev[i] = __expf(v[i] - m); s += ev[i]; }
  #pragma unroll
  for (int off = 32; off; off >>= 1) s += __shfl_xor(s, off);
  __syncthreads();
  if ((t & 63) == 0) red[wv] = s;
  __syncthreads();
  if (t < 16) {
    float x = red[t];
    #pragma unroll
    for (int off = 8; off; off >>= 1) x += __shfl_xor(x, off);
    red[t] = x;
  }
  __syncthreads();
  s = red[0];
  #pragma unroll
  for (int i = 0; i < 4; i++) w[(size_t)b * N_ + t + 1024 * i] = ev[i] / s;
}

// ---------------- bf16 NT GEMM: C[m,n] = sum_k A[m,k]*B[n,k] (+bias) ----------------
// MODE 0: plain store [M][768]; MODE 1: +bias; MODE 2: +bias, store vT[b][n][q]
template <int MODE>
__global__ __launch_bounds__(256) void gemm_nt_kernel(
    const unsigned short* __restrict__ A, const unsigned short* __restrict__ Bm,
    const float* __restrict__ bias, unsigned short* __restrict__ C) {
  constexpr int LDA = 40;
  __shared__ unsigned short As[64 * LDA];
  __shared__ unsigned short Bs[64 * LDA];
  int m0 = blockIdx.x * 64, n0 = blockIdx.y * 64;
  int t = threadIdx.x, wave = t >> 6, lane = t & 63;
  int wm = (wave & 1) * 32, wn = (wave >> 1) * 32;
  int fl = lane & 15, fq = lane >> 4;
  f32x4 acc[2][2];
  #pragma unroll
  for (int i = 0; i < 2; i++)
    #pragma unroll
    for (int j = 0; j < 2; j++) acc[i][j] = {0.f, 0.f, 0.f, 0.f};
  int sr = t >> 2, sc = (t & 3) * 8;
  for (int k0 = 0; k0 < D_; k0 += 32) {
    uint4 av = *(const uint4*)(A + (size_t)(m0 + sr) * D_ + k0 + sc);
    uint4 bv = *(const uint4*)(Bm + (size_t)(n0 + sr) * D_ + k0 + sc);
    __syncthreads();
    *(uint4*)(As + sr * LDA + sc) = av;
    *(uint4*)(Bs + sr * LDA + sc) = bv;
    __syncthreads();
    short8 afr[2], bfr[2];
    #pragma unroll
    for (int i = 0; i < 2; i++)
      afr[i] = *(const short8*)(As + (wm + i * 16 + fl) * LDA + fq * 8);
    #pragma unroll
    for (int j = 0; j < 2; j++)
      bfr[j] = *(const short8*)(Bs + (wn + j * 16 + fl) * LDA + fq * 8);
    #pragma unroll
    for (int i = 0; i < 2; i++)
      #pragma unroll
      for (int j = 0; j < 2; j++)
        acc[i][j] = __builtin_amdgcn_mfma_f32_16x16x32_bf16(afr[i], bfr[j], acc[i][j], 0, 0, 0);
  }
  #pragma unroll
  for (int i = 0; i < 2; i++)
    #pragma unroll
    for (int j = 0; j < 2; j++) {
      int n = n0 + wn + j * 16 + fl;
      float bb = (MODE >= 1) ? bias[n] : 0.f;
      #pragma unroll
      for (int r = 0; r < 4; r++) {
        int m = m0 + wm + i * 16 + fq * 4 + r;
        float val = acc[i][j][r] + bb;
        if (MODE == 2) {
          int bt = m >> 7, q = m & 127;
          C[((size_t)bt * D_ + n) * Q_ + q] = f2bf(val);
        } else {
          C[(size_t)m * D_ + n] = f2bf(val);
        }
      }
    }
}

// ---------------- skq[row] = dot(bq, k[row]) ----------------
__global__ __launch_bounds__(256) void bias_dot_kernel(
    const unsigned short* __restrict__ kb, const float* __restrict__ bq,
    float* __restrict__ skq) {
  int row = blockIdx.x * 4 + (threadIdx.x >> 6);
  int lane = threadIdx.x & 63;
  const unsigned short* kr = kb + (size_t)row * D_;
  float s = 0.f;
  for (int k = lane; k < D_; k += 64) s += bq[k] * bf2f(kr[k]);
  #pragma unroll
  for (int off = 32; off; off >>= 1) s += __shfl_xor(s, off);
  if (lane == 0) skq[row] = s;
}

// ---------------- fused attention main kernel ----------------
// per block: 128 tokens x full Q=128. S = vf*kq^T, softmax w/ ve*te modulation, O^T = vT*P^T
__global__ __launch_bounds__(256, 2) void attn_main_kernel(
    const float* __restrict__ vis,
    const unsigned short* __restrict__ kq,   // [B][Q][768] bf16
    const unsigned short* __restrict__ vT,   // [B][768][Q] bf16
    const float* __restrict__ ve,            // [B][4096]
    const float* __restrict__ te,            // [B][128]
    const float* __restrict__ skq,           // [B*Q]
    float* __restrict__ out)                 // [B][768][4096]
{
  constexpr int LA = 68;   // vf tile stride (bf16): 136B rows -> conflict-free b64 frags
  constexpr int LB = 72;   // kq tile stride: 144B rows -> 16B-aligned b128 frags
  constexpr int LP = 136;  // P and V strides: 272B rows
  // region aliasing: phaseA {As[128*68] | Bs[128*72]} ; then {Ps[128*136] | Vs[96*136]}
  __shared__ unsigned short region0[30464];       // 60928 B
  __shared__ float stats[2][128][2];
  unsigned short* As = region0;                   // bytes [0, 17408)
  unsigned short* Bs = region0 + 8704;            // bytes [17408, 35840)
  unsigned short* Ps = region0;                   // bytes [0, 34816)   (A/B dead)
  unsigned short* Vs = region0 + 17408;           // bytes [34816, 60928)

  const int bb = blockIdx.x >> 5;
  const int n0 = (blockIdx.x & 31) * 128;
  const int t = threadIdx.x;
  const int wave = t >> 6, lane = t & 63;
  const int fl = lane & 15, fq = lane >> 4;
  const int wm = (wave & 1) * 64;   // token half (phase A)
  const int wq = (wave >> 1) * 64;  // q half (phase A)

  const float* abase = vis + (size_t)bb * D_ * N_ + n0;
  const unsigned short* bbase = kq + (size_t)bb * Q_ * D_;

  f32x4 acc[4][4];
  #pragma unroll
  for (int i = 0; i < 4; i++)
    #pragma unroll
    for (int j = 0; j < 4; j++) acc[i][j] = {0.f, 0.f, 0.f, 0.f};

  const int smi = t & 127;
  const int ph = t >> 7;

  // ---------- phase A: S = vf * kq^T ----------
  for (int k0 = 0; k0 < D_; k0 += 64) {
    __syncthreads();
    // stage A (transpose fp32 [k][n] -> bf16 [m][k]), paired writes
    #pragma unroll
    for (int i = 0; i < 16; i++) {
      const int kk = 2 * (ph + 2 * i);
      const float v0 = abase[(size_t)(k0 + kk) * N_ + smi];
      const float v1 = abase[(size_t)(k0 + kk + 1) * N_ + smi];
      const unsigned pk = (unsigned)f2bf(v0) | ((unsigned)f2bf(v1) << 16);
      *(unsigned*)(As + smi * LA + kk) = pk;
    }
    // stage B (kq rows, contiguous k)
    #pragma unroll
    for (int i = 0; i < 4; i++) {
      const int c = t + 256 * i;
      const int q = c >> 3, kc = (c & 7) * 8;
      const uint4 v = *(const uint4*)(bbase + (size_t)q * D_ + k0 + kc);
      *(uint4*)(Bs + q * LB + kc) = v;
    }
    __syncthreads();
    #pragma unroll
    for (int ks = 0; ks < 2; ks++) {
      short8 afr[4], bfr[4];
      #pragma unroll
      for (int i = 0; i < 4; i++) {
        const unsigned short* pa = As + (wm + i * 16 + fl) * LA + ks * 32 + fq * 8;
        sv4 lo = *(const sv4*)pa;
        sv4 hi = *(const sv4*)(pa + 4);
        afr[i] = __builtin_shufflevector(lo, hi, 0, 1, 2, 3, 4, 5, 6, 7);
      }
      #pragma unroll
      for (int j = 0; j < 4; j++)
        bfr[j] = *(const short8*)(Bs + (wq + j * 16 + fl) * LB + ks * 32 + fq * 8);
      #pragma unroll
      for (int i = 0; i < 4; i++)
        #pragma unroll
        for (int j = 0; j < 4; j++)
          acc[i][j] = __builtin_amdgcn_mfma_f32_16x16x32_bf16(afr[i], bfr[j], acc[i][j], 0, 0, 0);
    }
  }

  // ---------- softmax with entropy modulation ----------
  const float rsD = 0.03608439182435161f;  // 1/sqrt(768)
  float tev[4], skv[4];
  #pragma unroll
  for (int j = 0; j < 4; j++) {
    int q = wq + j * 16 + fl;
    tev[j] = te[bb * Q_ + q];
    skv[j] = skq[bb * Q_ + q];
  }
  float vev4[4][4];
  #pragma unroll
  for (int i = 0; i < 4; i++)
    #pragma unroll
    for (int r = 0; r < 4; r++)
      vev4[i][r] = ve[(size_t)bb * N_ + n0 + wm + i * 16 + fq * 4 + r];

  float rmax[4][4], rsum[4][4];
  #pragma unroll
  for (int i = 0; i < 4; i++)
    #pragma unroll
    for (int r = 0; r < 4; r++) rmax[i][r] = -__builtin_inff();
  #pragma unroll
  for (int i = 0; i < 4; i++)
    #pragma unroll
    for (int j = 0; j < 4; j++)
      #pragma unroll
      for (int r = 0; r < 4; r++) {
        float L = (acc[i][j][r] + skv[j]) * rsD * vev4[i][r] * tev[j];
        acc[i][j][r] = L;
        rmax[i][r] = fmaxf(rmax[i][r], L);
      }
  #pragma unroll
  for (int off = 1; off < 16; off <<= 1)
    #pragma unroll
    for (int i = 0; i < 4; i++)
      #pragma unroll
      for (int r = 0; r < 4; r++)
        rmax[i][r] = fmaxf(rmax[i][r], __shfl_xor(rmax[i][r], off));
  #pragma unroll
  for (int i = 0; i < 4; i++)
    #pragma unroll
    for (int r = 0; r < 4; r++) rsum[i][r] = 0.f;
  #pragma unroll
  for (int i = 0; i < 4; i++)
    #pragma unroll
    for (int j = 0; j < 4; j++)
      #pragma unroll
      for (int r = 0; r < 4; r++) {
        float e = __expf(acc[i][j][r] - rmax[i][r]);
        acc[i][j][r] = e;
        rsum[i][r] += e;
      }
  #pragma unroll
  for (int off = 1; off < 16; off <<= 1)
    #pragma unroll
    for (int i = 0; i < 4; i++)
      #pragma unroll
      for (int r = 0; r < 4; r++) rsum[i][r] += __shfl_xor(rsum[i][r], off);

  const int qh = wq >> 6;
  if (fl == 0) {
    #pragma unroll
    for (int i = 0; i < 4; i++)
      #pragma unroll
      for (int r = 0; r < 4; r++) {
        int m = wm + i * 16 + fq * 4 + r;
        stats[qh][m][0] = rmax[i][r];
        stats[qh][m][1] = rsum[i][r];
      }
  }
  __syncthreads();  // also ensures ALL waves finished As/Bs reads before Ps overwrite
  float fac[4][4];
  #pragma unroll
  for (int i = 0; i < 4; i++)
    #pragma unroll
    for (int r = 0; r < 4; r++) {
      int m = wm + i * 16 + fq * 4 + r;
      float M2 = stats[1 - qh][m][0], S2 = stats[1 - qh][m][1];
      float Mf = fmaxf(rmax[i][r], M2);
      float sf = rsum[i][r] * __expf(rmax[i][r] - Mf) + S2 * __expf(M2 - Mf);
      fac[i][r] = __expf(rmax[i][r] - Mf) / sf;
    }
  #pragma unroll
  for (int i = 0; i < 4; i++)
    #pragma unroll
    for (int j = 0; j < 4; j++)
      #pragma unroll
      for (int r = 0; r < 4; r++) {
        int m = wm + i * 16 + fq * 4 + r;
        int q = wq + j * 16 + fl;
        Ps[m * LP + q] = f2bf(acc[i][j][r] * fac[i][r]);
      }

  // ---------- phase B: O^T = vT * P^T, d-chunks of 96 ----------
  const int wd = (wave & 1) * 48;   // d half within chunk
  const int wm2 = (wave >> 1) * 64; // token half
  for (int dc = 0; dc < 8; dc++) {
    __syncthreads();  // covers Ps writes (dc=0) and prior-chunk Vs reads
    const unsigned short* vbase = vT + ((size_t)bb * D_ + dc * 96) * Q_;
    #pragma unroll
    for (int i = 0; i < 6; i++) {
      const int c = t + 256 * i;
      const int d = c >> 4, qc = (c & 15) * 8;
      const uint4 v = *(const uint4*)(vbase + (size_t)d * Q_ + qc);
      *(uint4*)(Vs + d * LP + qc) = v;
    }
    __syncthreads();
    f32x4 acc2[3][4];
    #pragma unroll
    for (int i = 0; i < 3; i++)
      #pragma unroll
      for (int j = 0; j < 4; j++) acc2[i][j] = {0.f, 0.f, 0.f, 0.f};
    #pragma unroll
    for (int ks = 0; ks < 4; ks++) {
      short8 vfr[3], pfr[4];
      #pragma unroll
      for (int i = 0; i < 3; i++)
        vfr[i] = *(const short8*)(Vs + (wd + i * 16 + fl) * LP + ks * 32 + fq * 8);
      #pragma unroll
      for (int j = 0; j < 4; j++)
        pfr[j] = *(const short8*)(Ps + (wm2 + j * 16 + fl) * LP + ks * 32 + fq * 8);
      #pragma unroll
      for (int i = 0; i < 3; i++)
        #pragma unroll
        for (int j = 0; j < 4; j++)
          acc2[i][j] = __builtin_amdgcn_mfma_f32_16x16x32_bf16(vfr[i], pfr[j], acc2[i][j], 0, 0, 0);
    }
    float* obase = out + ((size_t)bb * D_ + dc * 96) * N_ + n0;
    #pragma unroll
    for (int i = 0; i < 3; i++)
      #pragma unroll
      for (int j = 0; j < 4; j++) {
        int mm = wm2 + j * 16 + fl;
        #pragma unroll
        for (int r = 0; r < 4; r++) {
          int d = wd + i * 16 + fq * 4 + r;
          obase[(size_t)d * N_ + mm] = acc2[i][j][r];
        }
      }
  }
}

extern "C" void kernel_launch(void* const* d_in, const int* in_sizes, int n_in,
                              void* d_out, int out_size, void* d_ws, size_t ws_size,
                              hipStream_t stream) {
  const float* vis  = (const float*)d_in[0];
  const float* text = (const float*)d_in[1];
  const float* Wq   = (const float*)d_in[2];
  const float* bq   = (const float*)d_in[3];
  const float* Wk   = (const float*)d_in[4];
  const float* bk   = (const float*)d_in[5];
  const float* Wv   = (const float*)d_in[6];
  const float* bv   = (const float*)d_in[7];
  float* out = (float*)d_out;
  char* ws = (char*)d_ws;

  unsigned short* textb = (unsigned short*)(ws + 0);
  unsigned short* Wkb   = (unsigned short*)(ws + 3145728);
  unsigned short* Wvb   = (unsigned short*)(ws + 4325376);
  unsigned short* WqTb  = (unsigned short*)(ws + 5505024);
  unsigned short* kb    = (unsigned short*)(ws + 6684672);
  unsigned short* kqb   = (unsigned short*)(ws + 9830400);
  unsigned short* vTb   = (unsigned short*)(ws + 12976128);
  float* ent_t = (float*)(ws + 16121856);
  float* tew   = (float*)(ws + 16130048);
  float* ent_v = (float*)(ws + 16138240);
  float* vew   = (float*)(ws + 16400384);
  float* skq   = (float*)(ws + 16662528);
  // total ws: 16,670,720 bytes

  cast_bf16_kernel<<<1536, 256, 0, stream>>>(text, textb, 2048 * 768 / 4);
  cast_bf16_kernel<<<576, 256, 0, stream>>>(Wk, Wkb, 768 * 768 / 4);
  cast_bf16_kernel<<<576, 256, 0, stream>>>(Wv, Wvb, 768 * 768 / 4);
  transpose_cast_kernel<<<dim3(24, 24), 256, 0, stream>>>(Wq, WqTb, 768, 768);

  row_entropy_kernel<<<512, 256, 0, stream>>>(text, ent_t, 768);
  softmax128_kernel<<<16, 128, 0, stream>>>(ent_t, tew);
  visual_entropy_kernel<<<1024, 256, 0, stream>>>(vis, ent_v);
  softmax4096_kernel<<<16, 1024, 0, stream>>>(ent_v, vew);

  gemm_nt_kernel<1><<<dim3(32, 12), 256, 0, stream>>>(textb, Wkb, bk, kb);    // k
  gemm_nt_kernel<2><<<dim3(32, 12), 256, 0, stream>>>(textb, Wvb, bv, vTb);   // v^T
  gemm_nt_kernel<0><<<dim3(32, 12), 256, 0, stream>>>(kb, WqTb, nullptr, kqb); // kq = k*Wq
  bias_dot_kernel<<<512, 256, 0, stream>>>(kb, bq, skq);

  attn_main_kernel<<<512, 256, 0, stream>>>(vis, kqb, vTb, vew, tew, skq, out);
}